// Round 6
// baseline (657.929 us; speedup 1.0000x reference)
//
#include <hip/hip_runtime.h>

// ShiftWindowMSA (Swin) fused kernels for MI355X (gfx950).
// B=16, H=W=64, C=512, NH=16, hd=32, WS=8, SS=4 -> 1024 windows x 64 tokens.
//
// R6: single fused kernel rebuilt from measured evidence:
//  - R5 split falsified (qkvbuf HBM round-trip: k_qkv 280us, WRITE 210MB).
//  - R1 fused fetched 173MB (110MB HBM weight re-fetch) -> XCD-grouped win
//    mapping (the schedule that measured 69MB in R5's k_qkv).
//  - Occupancy was register-capped (~2 waves/SIMD): 96-AGPR QKV acc + 64-VGPR
//    po. Fix: QKV split into q/k-pass (64 acc) + v-pass (32 acc); per-head y
//    written immediately to global yw (R5 k_attn2-proven write) and read back
//    by the proj phase (R5 k_proj2-proven read) after one __syncthreads().
//  - LDS = swizzled per-wave scratch only (R2-proven 6144 sh/wave = 24576 B).
// Tier C2 (ws >= 130 MiB): wcvt+xcvt+k_fused2.
// Tier B  (ws >=  66 MiB): R1 proven path (k_fused_r1, 403-409 us).
// Tier C  : R0 monolithic k_legacy.
// NEVER __launch_bounds__(256,3) (R2: 84-VGPR spill catastrophe).

typedef short  short8  __attribute__((ext_vector_type(8)));
typedef short  short4v __attribute__((ext_vector_type(4)));
typedef float  floatx4 __attribute__((ext_vector_type(4)));

#define DEVI static __device__ __forceinline__

DEVI unsigned short f2bf(float f) {
    union { float f; unsigned int u; } v;
    v.f = f;
    return (unsigned short)((v.u + 0x7fffu + ((v.u >> 16) & 1u)) >> 16);
}

// ---------------------------------------------------------------------------
// wcvt: qkv_w (1536x512) then proj_w (512x512) fp32 -> bf16 into wbf.
// ---------------------------------------------------------------------------
__global__ void wcvt(const float* __restrict__ qkv_w,
                     const float* __restrict__ proj_w,
                     unsigned short* __restrict__ wbf) {
    const int idx = ((blockIdx.x << 8) + threadIdx.x) << 2;
    const float* src = (idx < 786432) ? (qkv_w + idx) : (proj_w + (idx - 786432));
    const floatx4 v = *(const floatx4*)src;
    short4v o;
    o[0] = (short)f2bf(v[0]); o[1] = (short)f2bf(v[1]);
    o[2] = (short)f2bf(v[2]); o[3] = (short)f2bf(v[3]);
    *(short4v*)(wbf + idx) = o;
}

// ---------------------------------------------------------------------------
// xcvt: gather cyclic-shifted windows of query -> xw bf16 [win][kc][tok][32].
// Grid 16384; window w handled by blocks with bid%8 == w/128 (XCD grouping).
// ---------------------------------------------------------------------------
__global__ void xcvt(const float* __restrict__ query,
                     unsigned short* __restrict__ xw) {
    const int bid = blockIdx.x;
    const int x   = bid & 7;
    const int s   = bid >> 3;                           // 0..2047
    const int win = (x << 7) + (s >> 4);
    const int rem = ((s & 15) << 8) + threadIdx.x;      // 0..4095
    const int jc  = rem & 3;                            // 8-short chunk in 32
    const int tok = (rem >> 2) & 63;
    const int kc  = rem >> 8;                           // 0..15
    const int b   = win >> 6, wy = (win >> 3) & 7, wx = win & 7;
    const int ty  = tok >> 3, tx = tok & 7;
    const int gh  = ((wy << 3) + ty + 4) & 63;
    const int gw  = ((wx << 3) + tx + 4) & 63;
    const float* src = query + (((b << 12) + (gh << 6) + gw) << 9) + (kc << 5) + (jc << 3);
    const floatx4 v0 = *(const floatx4*)src;
    const floatx4 v1 = *(const floatx4*)(src + 4);
    short8 sv;
    sv[0] = (short)f2bf(v0[0]); sv[1] = (short)f2bf(v0[1]);
    sv[2] = (short)f2bf(v0[2]); sv[3] = (short)f2bf(v0[3]);
    sv[4] = (short)f2bf(v1[0]); sv[5] = (short)f2bf(v1[1]);
    sv[6] = (short)f2bf(v1[2]); sv[7] = (short)f2bf(v1[3]);
    *(short8*)(xw + (win << 15) + (kc << 11) + (tok << 5) + (jc << 3)) = sv;
}

// ---------------------------------------------------------------------------
// k_fused2: grid 1024, 1 block = 1 window (XCD-grouped), 4 waves x 4 heads.
// Per wave per head: q/k GEMM pass -> LDS (swizzled) -> v GEMM pass -> vT LDS
// -> QK^T -> softmax -> PV -> y head-tile to global yw. Then barrier and the
// proj GEMM reads yw (L2-hot, same block) and scatters to out.
// ---------------------------------------------------------------------------
__global__ __launch_bounds__(256, 2)
void k_fused2(const unsigned short* __restrict__ wbf,
              const unsigned short* __restrict__ xw,
              unsigned short* __restrict__ yw,
              const float* __restrict__ qkv_b,
              const float* __restrict__ proj_b,
              const float* __restrict__ bias_table,
              float* __restrict__ out)
{
    __shared__ __align__(16) unsigned short smem[24576];   // 4 waves * 6144

    const int tid  = threadIdx.x;
    const int lane = tid & 63;
    const int l15  = lane & 15;
    const int quad = lane >> 4;
    const int wave = tid >> 6;

    const int bid = blockIdx.x;
    const int win = ((bid & 7) << 7) + (bid >> 3);      // XCD-grouped (matches xcvt)
    const int b   = win >> 6;
    const int wy  = (win >> 3) & 7;
    const int wx  = win & 7;
    const int mid = ((wy == 7) ? 2 : 0) | ((wx == 7) ? 1 : 0);

    unsigned short* wbs = smem + wave * 6144;
    unsigned short* qbf = wbs;                          // [64][32] swizzled
    unsigned short* kbf = wbs + 2048;                   // [64][32] swizzled
    unsigned short* vT  = wbs + 4096;                   // [32][64] swizzled
    unsigned short* pbf = wbs;                          // [64][64] swizzled, overlays q+k

    const int sw4 = (l15 & 3) ^ (l15 >> 2);             // q/k read swizzle
    const int sw8 = (l15 & 7) ^ (l15 >> 3);             // vT/p read swizzle

    const unsigned short* xa = xw + (win << 15) + (l15 << 5) + (quad << 3);
    const float scale = 0.17677669529663687f;           // 1/sqrt(32)
    const floatx4 fz = {0.f, 0.f, 0.f, 0.f};

    for (int hh = 0; hh < 4; ++hh) {
        const int h = (wave << 2) + hh;

        // ---------------- pass 1: q,k projection (acc = 64 regs) ------------
        floatx4 accq[4][2], acck[4][2];
        #pragma unroll
        for (int mt = 0; mt < 4; ++mt)
            #pragma unroll
            for (int nt = 0; nt < 2; ++nt) { accq[mt][nt] = fz; acck[mt][nt] = fz; }

        const unsigned short* wq = wbf + ((h << 5) + l15) * 512 + (quad << 3);
        const unsigned short* wk = wq + 262144;

        #pragma unroll 2
        for (int kk = 0; kk < 512; kk += 32) {
            short8 a[4], bq[2], bk2[2];
            #pragma unroll
            for (int mt = 0; mt < 4; ++mt)
                a[mt] = *(const short8*)(xa + (kk << 6) + (mt << 9));
            #pragma unroll
            for (int nt = 0; nt < 2; ++nt) {
                const int ro = (nt << 4) * 512 + kk;
                bq[nt]  = *(const short8*)(wq + ro);
                bk2[nt] = *(const short8*)(wk + ro);
            }
            #pragma unroll
            for (int nt = 0; nt < 2; ++nt)
                #pragma unroll
                for (int mt = 0; mt < 4; ++mt) {
                    accq[mt][nt] = __builtin_amdgcn_mfma_f32_16x16x32_bf16(a[mt], bq[nt],  accq[mt][nt], 0, 0, 0);
                    acck[mt][nt] = __builtin_amdgcn_mfma_f32_16x16x32_bf16(a[mt], bk2[nt], acck[mt][nt], 0, 0, 0);
                }
        }

        // bias + stage q,k into swizzled LDS (R2-proven layout)
        #pragma unroll
        for (int nt = 0; nt < 2; ++nt) {
            const int cix = (h << 5) + (nt << 4) + l15;
            const float bq_ = qkv_b[cix];
            const float bk_ = qkv_b[512 + cix];
            #pragma unroll
            for (int mt = 0; mt < 4; ++mt)
                #pragma unroll
                for (int r = 0; r < 4; ++r) {
                    const int row = (mt << 4) + (quad << 2) + r;
                    const int ph  = (2 * nt + (l15 >> 3)) ^ (row & 3) ^ ((row >> 2) & 3);
                    const int off = (row << 5) + (l15 & 7) + (ph << 3);
                    qbf[off] = f2bf(accq[mt][nt][r] + bq_);
                    kbf[off] = f2bf(acck[mt][nt][r] + bk_);
                }
        }

        // ---------------- pass 2: v projection (acc = 32 regs) --------------
        floatx4 accv[4][2];
        #pragma unroll
        for (int mt = 0; mt < 4; ++mt)
            #pragma unroll
            for (int nt = 0; nt < 2; ++nt) accv[mt][nt] = fz;

        const unsigned short* wv = wbf + 524288 + ((h << 5) + l15) * 512 + (quad << 3);

        #pragma unroll 2
        for (int kk = 0; kk < 512; kk += 32) {
            short8 a[4], bv2[2];
            #pragma unroll
            for (int mt = 0; mt < 4; ++mt)
                a[mt] = *(const short8*)(xa + (kk << 6) + (mt << 9));
            #pragma unroll
            for (int nt = 0; nt < 2; ++nt)
                bv2[nt] = *(const short8*)(wv + (nt << 4) * 512 + kk);
            #pragma unroll
            for (int nt = 0; nt < 2; ++nt)
                #pragma unroll
                for (int mt = 0; mt < 4; ++mt)
                    accv[mt][nt] = __builtin_amdgcn_mfma_f32_16x16x32_bf16(a[mt], bv2[nt], accv[mt][nt], 0, 0, 0);
        }

        // bias + stage v transposed into swizzled LDS (R2-proven layout)
        #pragma unroll
        for (int nt = 0; nt < 2; ++nt) {
            const float bv_ = qkv_b[1024 + (h << 5) + (nt << 4) + l15];
            #pragma unroll
            for (int mt = 0; mt < 4; ++mt) {
                short4v vv;
                #pragma unroll
                for (int r = 0; r < 4; ++r)
                    vv[r] = (short)f2bf(accv[mt][nt][r] + bv_);
                const int vph = (2 * mt + (quad >> 1)) ^ sw8;
                *(short4v*)&vT[(((nt << 4) + l15) << 6) + ((quad & 1) << 2) + (vph << 3)] = vv;
            }
        }
        // (no barrier: scratch is wave-private)

        // ---------------- Q K^T ---------------------------------------------
        short8 qa[4], ka[4];
        #pragma unroll
        for (int t = 0; t < 4; ++t) {
            const int off = ((((t << 4) + l15)) << 5) + ((quad ^ sw4) << 3);
            qa[t] = *(const short8*)&qbf[off];
            ka[t] = *(const short8*)&kbf[off];
        }
        floatx4 s4[4][4];
        #pragma unroll
        for (int mt = 0; mt < 4; ++mt)
            #pragma unroll
            for (int nt = 0; nt < 4; ++nt)
                s4[mt][nt] = __builtin_amdgcn_mfma_f32_16x16x32_bf16(qa[mt], ka[nt], fz, 0, 0, 0);

        // ------- logits: scale + rel-pos bias (closed-form idx) + shift mask -
        int  gjv[4]; bool jrow[4], jcol[4];
        #pragma unroll
        for (int nt = 0; nt < 4; ++nt) {
            const int j  = (nt << 4) + l15;
            const int j2 = 63 - j;
            gjv[nt]  = 15 * (j2 >> 3) + (j2 & 7);
            jrow[nt] = (j >> 3) < 4;
            jcol[nt] = (j & 7) < 4;
        }
        #pragma unroll
        for (int mt = 0; mt < 4; ++mt) {
            const int i0  = (mt << 4) + (quad << 2);
            const int fi0 = 15 * (i0 >> 3) + (i0 & 7);
            const bool irow = (i0 >> 3) < 4;
            const bool icol = (i0 & 7) == 0;
            #pragma unroll
            for (int nt = 0; nt < 4; ++nt) {
                float mval = 0.0f;
                if ((mid & 2) && (irow != jrow[nt])) mval = -100.0f;
                if ((mid & 1) && (icol != jcol[nt])) mval = -100.0f;
                const float* bp = bias_table + (fi0 + gjv[nt]) * 16 + h;
                #pragma unroll
                for (int r = 0; r < 4; ++r)
                    s4[mt][nt][r] = s4[mt][nt][r] * scale + bp[r * 16] + mval;
            }
        }

        // ---- softmax (max-subtracted, normalized) -> P in swizzled LDS ------
        #pragma unroll
        for (int mt = 0; mt < 4; ++mt)
            #pragma unroll
            for (int r = 0; r < 4; ++r) {
                float m = fmaxf(fmaxf(s4[mt][0][r], s4[mt][1][r]),
                                fmaxf(s4[mt][2][r], s4[mt][3][r]));
                m = fmaxf(m, __shfl_xor(m, 1));
                m = fmaxf(m, __shfl_xor(m, 2));
                m = fmaxf(m, __shfl_xor(m, 4));
                m = fmaxf(m, __shfl_xor(m, 8));
                float loc = 0.0f;
                #pragma unroll
                for (int nt = 0; nt < 4; ++nt) {
                    s4[mt][nt][r] = __expf(s4[mt][nt][r] - m);
                    loc += s4[mt][nt][r];
                }
                loc += __shfl_xor(loc, 1);
                loc += __shfl_xor(loc, 2);
                loc += __shfl_xor(loc, 4);
                loc += __shfl_xor(loc, 8);
                const float inv = 1.0f / loc;           // loc >= 1 (max entry = 1)
                const int row = (mt << 4) + (quad << 2) + r;
                #pragma unroll
                for (int nt = 0; nt < 4; ++nt) {
                    const int ph = (2 * nt + (l15 >> 3)) ^ (row & 7) ^ ((row >> 3) & 1);
                    pbf[(row << 6) + (l15 & 7) + (ph << 3)] = f2bf(s4[mt][nt][r] * inv);
                }
            }
        // (no barrier: pbf is wave-private)

        // ---------------- P V -> y head-tile to global yw --------------------
        short8 pa[4][2], va[2][2];
        #pragma unroll
        for (int mt = 0; mt < 4; ++mt)
            #pragma unroll
            for (int ks = 0; ks < 2; ++ks)
                pa[mt][ks] = *(const short8*)&pbf[((((mt << 4) + l15)) << 6) + ((((ks << 2) + quad) ^ sw8) << 3)];
        #pragma unroll
        for (int nt = 0; nt < 2; ++nt)
            #pragma unroll
            for (int ks = 0; ks < 2; ++ks)
                va[nt][ks] = *(const short8*)&vT[((((nt << 4) + l15)) << 6) + ((((ks << 2) + quad) ^ sw8) << 3)];

        unsigned short* yh = yw + (win << 15) + (h << 11);
        #pragma unroll
        for (int mt = 0; mt < 4; ++mt)
            #pragma unroll
            for (int nt = 0; nt < 2; ++nt) {
                floatx4 acc = fz;
                acc = __builtin_amdgcn_mfma_f32_16x16x32_bf16(pa[mt][0], va[nt][0], acc, 0, 0, 0);
                acc = __builtin_amdgcn_mfma_f32_16x16x32_bf16(pa[mt][1], va[nt][1], acc, 0, 0, 0);
                #pragma unroll
                for (int r = 0; r < 4; ++r) {
                    const int tok = (mt << 4) + (quad << 2) + r;
                    yh[(tok << 5) + (nt << 4) + l15] = f2bf(acc[r]);
                }
            }
    }

    __syncthreads();   // all waves' y written; intra-block global visibility

    // ---------------- proj GEMM (reads yw, L2-hot) + reverse scatter ---------
    const int th = wave & 1;                            // token half
    const int cq = wave >> 1;                           // channel 128-half
    const unsigned short* ya  = yw + (win << 15) + (l15 << 5) + (quad << 3);
    const unsigned short* pwb = wbf + 786432;           // proj_w bf16

    for (int pass = 0; pass < 2; ++pass) {
        const int co0 = (pass << 8) + (cq << 7);
        floatx4 acc[2][8];
        #pragma unroll
        for (int mt = 0; mt < 2; ++mt)
            #pragma unroll
            for (int nt = 0; nt < 8; ++nt) acc[mt][nt] = fz;

        const unsigned short* wp = pwb + (co0 + l15) * 512 + (quad << 3);

        #pragma unroll 2
        for (int kk = 0; kk < 512; kk += 32) {
            short8 a[2], bfr[8];
            #pragma unroll
            for (int mt = 0; mt < 2; ++mt)
                a[mt] = *(const short8*)(ya + (kk << 6) + (((th << 1) + mt) << 9));
            #pragma unroll
            for (int nt = 0; nt < 8; ++nt)
                bfr[nt] = *(const short8*)(wp + (nt << 4) * 512 + kk);
            #pragma unroll
            for (int nt = 0; nt < 8; ++nt)
                #pragma unroll
                for (int mt = 0; mt < 2; ++mt)
                    acc[mt][nt] = __builtin_amdgcn_mfma_f32_16x16x32_bf16(a[mt], bfr[nt], acc[mt][nt], 0, 0, 0);
        }

        #pragma unroll
        for (int nt = 0; nt < 8; ++nt) {
            const float pb_ = proj_b[co0 + (nt << 4) + l15];
            #pragma unroll
            for (int mt = 0; mt < 2; ++mt)
                #pragma unroll
                for (int r = 0; r < 4; ++r) {
                    const int tok = (((th << 1) + mt) << 4) + (quad << 2) + r;
                    const int ty = tok >> 3, tx = tok & 7;
                    const int gh = ((wy << 3) + ty + 4) & 63;
                    const int gw = ((wx << 3) + tx + 4) & 63;
                    out[(((b << 12) + (gh << 6) + gw) << 9) + co0 + (nt << 4) + l15] =
                        acc[mt][nt][r] + pb_;
                }
        }
    }
}

// ---------------------------------------------------------------------------
// Tier B: R1's proven fused kernel (QKV+attn+proj from pre-tiled xw).
// ---------------------------------------------------------------------------
__global__ __launch_bounds__(256, 2)
void k_fused_r1(const unsigned short* __restrict__ wbf,
                const unsigned short* __restrict__ xw,
                const float* __restrict__ qkv_b,
                const float* __restrict__ proj_b,
                const float* __restrict__ bias_table,
                float* __restrict__ out)
{
    __shared__ __align__(16) unsigned short smem[33280];

    const int tid  = threadIdx.x;
    const int lane = tid & 63;
    const int l15  = lane & 15;
    const int quad = lane >> 4;
    const int wave = tid >> 6;

    const int win = blockIdx.x;
    const int b   = win >> 6;
    const int wy  = (win >> 3) & 7;
    const int wx  = win & 7;
    const int mid = ((wy == 7) ? 2 : 0) | ((wx == 7) ? 1 : 0);

    unsigned short* xs  = smem;
    unsigned short* wb  = smem + wave * 7424;
    unsigned short* qbf = wb;
    unsigned short* kbf = wb + 2560;
    unsigned short* vT  = wb + 5120;
    unsigned short* pbf = wb;

    const unsigned short* xa = xw + (win << 15) + (l15 << 5) + (quad << 3);
    const float scale = 0.17677669529663687f;
    const floatx4 fz = {0.f, 0.f, 0.f, 0.f};
    unsigned int po[4][16];

    for (int hh = 0; hh < 4; ++hh) {
        const int h = (wave << 2) + hh;
        floatx4 accq[4][2], acck[4][2], accv[4][2];
        #pragma unroll
        for (int mt = 0; mt < 4; ++mt)
            #pragma unroll
            for (int nt = 0; nt < 2; ++nt) { accq[mt][nt] = fz; acck[mt][nt] = fz; accv[mt][nt] = fz; }

        const unsigned short* wq = wbf + ((h << 5) + l15) * 512 + (quad << 3);
        const unsigned short* wk = wq + 512 * 512;
        const unsigned short* wv = wk + 512 * 512;

        #pragma unroll 2
        for (int kk = 0; kk < 512; kk += 32) {
            short8 a[4], bq[2], bk2[2], bv2[2];
            #pragma unroll
            for (int mt = 0; mt < 4; ++mt)
                a[mt] = *(const short8*)(xa + (kk << 6) + (mt << 9));
            #pragma unroll
            for (int nt = 0; nt < 2; ++nt) {
                const int ro = (nt << 4) * 512 + kk;
                bq[nt]  = *(const short8*)(wq + ro);
                bk2[nt] = *(const short8*)(wk + ro);
                bv2[nt] = *(const short8*)(wv + ro);
            }
            #pragma unroll
            for (int nt = 0; nt < 2; ++nt)
                #pragma unroll
                for (int mt = 0; mt < 4; ++mt) {
                    accq[mt][nt] = __builtin_amdgcn_mfma_f32_16x16x32_bf16(a[mt], bq[nt],  accq[mt][nt], 0, 0, 0);
                    acck[mt][nt] = __builtin_amdgcn_mfma_f32_16x16x32_bf16(a[mt], bk2[nt], acck[mt][nt], 0, 0, 0);
                    accv[mt][nt] = __builtin_amdgcn_mfma_f32_16x16x32_bf16(a[mt], bv2[nt], accv[mt][nt], 0, 0, 0);
                }
        }

        #pragma unroll
        for (int nt = 0; nt < 2; ++nt) {
            const int cix = (h << 5) + (nt << 4) + l15;
            const float bq_ = qkv_b[cix];
            const float bk_ = qkv_b[512 + cix];
            const float bv_ = qkv_b[1024 + cix];
            #pragma unroll
            for (int mt = 0; mt < 4; ++mt) {
                short4v vv;
                #pragma unroll
                for (int r = 0; r < 4; ++r) {
                    const int row = (mt << 4) + (quad << 2) + r;
                    qbf[row * 40 + (nt << 4) + l15] = f2bf(accq[mt][nt][r] + bq_);
                    kbf[row * 40 + (nt << 4) + l15] = f2bf(acck[mt][nt][r] + bk_);
                    vv[r] = (short)f2bf(accv[mt][nt][r] + bv_);
                }
                *(short4v*)&vT[((nt << 4) + l15) * 72 + (mt << 4) + (quad << 2)] = vv;
            }
        }

        short8 qa[4], ka[4];
        #pragma unroll
        for (int t = 0; t < 4; ++t) {
            qa[t] = *(const short8*)&qbf[((t << 4) + l15) * 40 + (quad << 3)];
            ka[t] = *(const short8*)&kbf[((t << 4) + l15) * 40 + (quad << 3)];
        }
        floatx4 s4[4][4];
        #pragma unroll
        for (int mt = 0; mt < 4; ++mt)
            #pragma unroll
            for (int nt = 0; nt < 4; ++nt)
                s4[mt][nt] = __builtin_amdgcn_mfma_f32_16x16x32_bf16(qa[mt], ka[nt], fz, 0, 0, 0);

        int  gjv[4]; bool jrow[4], jcol[4];
        #pragma unroll
        for (int nt = 0; nt < 4; ++nt) {
            const int j  = (nt << 4) + l15;
            const int j2 = 63 - j;
            gjv[nt]  = 15 * (j2 >> 3) + (j2 & 7);
            jrow[nt] = (j >> 3) < 4;
            jcol[nt] = (j & 7) < 4;
        }
        #pragma unroll
        for (int mt = 0; mt < 4; ++mt) {
            const int i0  = (mt << 4) + (quad << 2);
            const int fi0 = 15 * (i0 >> 3) + (i0 & 7);
            const bool irow = (i0 >> 3) < 4;
            const bool icol = (i0 & 7) == 0;
            #pragma unroll
            for (int nt = 0; nt < 4; ++nt) {
                float mval = 0.0f;
                if ((mid & 2) && (irow != jrow[nt])) mval = -100.0f;
                if ((mid & 1) && (icol != jcol[nt])) mval = -100.0f;
                const float* bp = bias_table + (fi0 + gjv[nt]) * 16 + h;
                #pragma unroll
                for (int r = 0; r < 4; ++r)
                    s4[mt][nt][r] = s4[mt][nt][r] * scale + bp[r * 16] + mval;
            }
        }

        #pragma unroll
        for (int mt = 0; mt < 4; ++mt)
            #pragma unroll
            for (int r = 0; r < 4; ++r) {
                float m = fmaxf(fmaxf(s4[mt][0][r], s4[mt][1][r]),
                                fmaxf(s4[mt][2][r], s4[mt][3][r]));
                m = fmaxf(m, __shfl_xor(m, 1));
                m = fmaxf(m, __shfl_xor(m, 2));
                m = fmaxf(m, __shfl_xor(m, 4));
                m = fmaxf(m, __shfl_xor(m, 8));
                float loc = 0.0f;
                #pragma unroll
                for (int nt = 0; nt < 4; ++nt) {
                    s4[mt][nt][r] = __expf(s4[mt][nt][r] - m);
                    loc += s4[mt][nt][r];
                }
                loc += __shfl_xor(loc, 1);
                loc += __shfl_xor(loc, 2);
                loc += __shfl_xor(loc, 4);
                loc += __shfl_xor(loc, 8);
                const float inv = 1.0f / loc;
                const int row = (mt << 4) + (quad << 2) + r;
                #pragma unroll
                for (int nt = 0; nt < 4; ++nt)
                    pbf[row * 72 + (nt << 4) + l15] = f2bf(s4[mt][nt][r] * inv);
            }

        short8 pa[4][2], va[2][2];
        #pragma unroll
        for (int mt = 0; mt < 4; ++mt)
            #pragma unroll
            for (int ks = 0; ks < 2; ++ks)
                pa[mt][ks] = *(const short8*)&pbf[((mt << 4) + l15) * 72 + (ks << 5) + (quad << 3)];
        #pragma unroll
        for (int nt = 0; nt < 2; ++nt)
            #pragma unroll
            for (int ks = 0; ks < 2; ++ks)
                va[nt][ks] = *(const short8*)&vT[((nt << 4) + l15) * 72 + (ks << 5) + (quad << 3)];

        #pragma unroll
        for (int mt = 0; mt < 4; ++mt)
            #pragma unroll
            for (int nt = 0; nt < 2; ++nt) {
                floatx4 acc = fz;
                acc = __builtin_amdgcn_mfma_f32_16x16x32_bf16(pa[mt][0], va[nt][0], acc, 0, 0, 0);
                acc = __builtin_amdgcn_mfma_f32_16x16x32_bf16(pa[mt][1], va[nt][1], acc, 0, 0, 0);
                const int pi = ((mt << 1) + nt) << 1;
                po[hh][pi]     = (unsigned int)f2bf(acc[0]) | ((unsigned int)f2bf(acc[1]) << 16);
                po[hh][pi + 1] = (unsigned int)f2bf(acc[2]) | ((unsigned int)f2bf(acc[3]) << 16);
            }
    }
    __syncthreads();

    #pragma unroll
    for (int hh = 0; hh < 4; ++hh) {
        const int ch0 = (((wave << 2) + hh) << 5) + l15;
        #pragma unroll
        for (int mt = 0; mt < 4; ++mt)
            #pragma unroll
            for (int nt = 0; nt < 2; ++nt) {
                const int pi = ((mt << 1) + nt) << 1;
                #pragma unroll
                for (int r = 0; r < 4; ++r) {
                    const int row = (mt << 4) + (quad << 2) + r;
                    const unsigned int w = po[hh][pi + (r >> 1)];
                    xs[row * 520 + ch0 + (nt << 4)] =
                        (unsigned short)((w >> ((r & 1) << 4)) & 0xffffu);
                }
            }
    }
    __syncthreads();

    const unsigned short* pwb = wbf + 786432;
    for (int pass = 0; pass < 2; ++pass) {
        const int co0 = (wave << 7) + (pass << 6);
        floatx4 acc[4][4];
        #pragma unroll
        for (int mt = 0; mt < 4; ++mt)
            #pragma unroll
            for (int nt = 0; nt < 4; ++nt) acc[mt][nt] = fz;

        const unsigned short* wp = pwb + (co0 + l15) * 512 + (quad << 3);

        #pragma unroll 2
        for (int kk = 0; kk < 512; kk += 32) {
            short8 a[4], bfr[4];
            #pragma unroll
            for (int mt = 0; mt < 4; ++mt)
                a[mt] = *(const short8*)&xs[((mt << 4) + l15) * 520 + kk + (quad << 3)];
            #pragma unroll
            for (int nt = 0; nt < 4; ++nt)
                bfr[nt] = *(const short8*)(wp + (nt << 4) * 512 + kk);
            #pragma unroll
            for (int nt = 0; nt < 4; ++nt)
                #pragma unroll
                for (int mt = 0; mt < 4; ++mt)
                    acc[mt][nt] = __builtin_amdgcn_mfma_f32_16x16x32_bf16(a[mt], bfr[nt], acc[mt][nt], 0, 0, 0);
        }

        #pragma unroll
        for (int nt = 0; nt < 4; ++nt) {
            const float pb_ = proj_b[co0 + (nt << 4) + l15];
            #pragma unroll
            for (int mt = 0; mt < 4; ++mt)
                #pragma unroll
                for (int r = 0; r < 4; ++r) {
                    const int tok = (mt << 4) + (quad << 2) + r;
                    const int ty = tok >> 3, tx = tok & 7;
                    const int gh = ((wy << 3) + ty + 4) & 63;
                    const int gw = ((wx << 3) + tx + 4) & 63;
                    out[(((b << 12) + (gh << 6) + gw) << 9) + co0 + (nt << 4) + l15] =
                        acc[mt][nt][r] + pb_;
                }
        }
    }
}

// ---------------------------------------------------------------------------
// Tier C: R0 monolithic fallback (stages window in LDS; ws needs only 2 MiB).
// ---------------------------------------------------------------------------
__global__ __launch_bounds__(256, 1)
void k_legacy(const float* __restrict__ query,
              const unsigned short* __restrict__ wbf,
              const float* __restrict__ qkv_b,
              const float* __restrict__ proj_b,
              const float* __restrict__ bias_table,
              float* __restrict__ out)
{
    __shared__ __align__(16) unsigned short smem[62976];

    const int tid  = threadIdx.x;
    const int lane = tid & 63;
    const int l15  = lane & 15;
    const int quad = lane >> 4;
    const int wave = tid >> 6;

    const int win = blockIdx.x;
    const int b   = win >> 6;
    const int wy  = (win >> 3) & 7;
    const int wx  = win & 7;
    const int mid = ((wy == 7) ? 2 : 0) | ((wx == 7) ? 1 : 0);

    unsigned short* xs  = smem;
    unsigned short* wb  = smem + 33280 + wave * 7424;
    unsigned short* qbf = wb;
    unsigned short* kbf = wb + 2560;
    unsigned short* vT  = wb + 5120;
    unsigned short* pbf = wb;

    #pragma unroll
    for (int it = 0; it < 32; ++it) {
        const int c   = tid + (it << 8);
        const int tok = c >> 7;
        const int fo  = (c & 127) << 2;
        const int ty  = tok >> 3, tx = tok & 7;
        const int gh  = ((wy << 3) + ty + 4) & 63;
        const int gw  = ((wx << 3) + tx + 4) & 63;
        const floatx4 v = *(const floatx4*)(query + (((b << 12) + (gh << 6) + gw) << 9) + fo);
        short4v s;
        s[0] = (short)f2bf(v[0]); s[1] = (short)f2bf(v[1]);
        s[2] = (short)f2bf(v[2]); s[3] = (short)f2bf(v[3]);
        *(short4v*)&xs[tok * 520 + fo] = s;
    }
    __syncthreads();

    const float scale = 0.17677669529663687f;
    const floatx4 fz = {0.f, 0.f, 0.f, 0.f};
    unsigned int po[4][16];

    for (int hh = 0; hh < 4; ++hh) {
        const int h = (wave << 2) + hh;
        floatx4 accq[4][2], acck[4][2], accv[4][2];
        #pragma unroll
        for (int mt = 0; mt < 4; ++mt)
            #pragma unroll
            for (int nt = 0; nt < 2; ++nt) { accq[mt][nt] = fz; acck[mt][nt] = fz; accv[mt][nt] = fz; }

        const unsigned short* wq = wbf + ((h << 5) + l15) * 512 + (quad << 3);
        const unsigned short* wk = wq + 512 * 512;
        const unsigned short* wv = wk + 512 * 512;

        #pragma unroll 2
        for (int kk = 0; kk < 512; kk += 32) {
            short8 a[4], bq[2], bk2[2], bv2[2];
            #pragma unroll
            for (int mt = 0; mt < 4; ++mt)
                a[mt] = *(const short8*)&xs[((mt << 4) + l15) * 520 + kk + (quad << 3)];
            #pragma unroll
            for (int nt = 0; nt < 2; ++nt) {
                const int ro = (nt << 4) * 512 + kk;
                bq[nt]  = *(const short8*)(wq + ro);
                bk2[nt] = *(const short8*)(wk + ro);
                bv2[nt] = *(const short8*)(wv + ro);
            }
            #pragma unroll
            for (int nt = 0; nt < 2; ++nt)
                #pragma unroll
                for (int mt = 0; mt < 4; ++mt) {
                    accq[mt][nt] = __builtin_amdgcn_mfma_f32_16x16x32_bf16(a[mt], bq[nt],  accq[mt][nt], 0, 0, 0);
                    acck[mt][nt] = __builtin_amdgcn_mfma_f32_16x16x32_bf16(a[mt], bk2[nt], acck[mt][nt], 0, 0, 0);
                    accv[mt][nt] = __builtin_amdgcn_mfma_f32_16x16x32_bf16(a[mt], bv2[nt], accv[mt][nt], 0, 0, 0);
                }
        }

        #pragma unroll
        for (int nt = 0; nt < 2; ++nt) {
            const int cix = (h << 5) + (nt << 4) + l15;
            const float bq_ = qkv_b[cix];
            const float bk_ = qkv_b[512 + cix];
            const float bv_ = qkv_b[1024 + cix];
            #pragma unroll
            for (int mt = 0; mt < 4; ++mt) {
                short4v vv;
                #pragma unroll
                for (int r = 0; r < 4; ++r) {
                    const int row = (mt << 4) + (quad << 2) + r;
                    qbf[row * 40 + (nt << 4) + l15] = f2bf(accq[mt][nt][r] + bq_);
                    kbf[row * 40 + (nt << 4) + l15] = f2bf(acck[mt][nt][r] + bk_);
                    vv[r] = (short)f2bf(accv[mt][nt][r] + bv_);
                }
                *(short4v*)&vT[((nt << 4) + l15) * 72 + (mt << 4) + (quad << 2)] = vv;
            }
        }

        short8 qa[4], ka[4];
        #pragma unroll
        for (int t = 0; t < 4; ++t) {
            qa[t] = *(const short8*)&qbf[((t << 4) + l15) * 40 + (quad << 3)];
            ka[t] = *(const short8*)&kbf[((t << 4) + l15) * 40 + (quad << 3)];
        }
        floatx4 s4[4][4];
        #pragma unroll
        for (int mt = 0; mt < 4; ++mt)
            #pragma unroll
            for (int nt = 0; nt < 4; ++nt)
                s4[mt][nt] = __builtin_amdgcn_mfma_f32_16x16x32_bf16(qa[mt], ka[nt], fz, 0, 0, 0);

        int  gjv[4]; bool jrow[4], jcol[4];
        #pragma unroll
        for (int nt = 0; nt < 4; ++nt) {
            const int j  = (nt << 4) + l15;
            const int j2 = 63 - j;
            gjv[nt]  = 15 * (j2 >> 3) + (j2 & 7);
            jrow[nt] = (j >> 3) < 4;
            jcol[nt] = (j & 7) < 4;
        }
        #pragma unroll
        for (int mt = 0; mt < 4; ++mt) {
            const int i0  = (mt << 4) + (quad << 2);
            const int fi0 = 15 * (i0 >> 3) + (i0 & 7);
            const bool irow = (i0 >> 3) < 4;
            const bool icol = (i0 & 7) == 0;
            #pragma unroll
            for (int nt = 0; nt < 4; ++nt) {
                float mval = 0.0f;
                if ((mid & 2) && (irow != jrow[nt])) mval = -100.0f;
                if ((mid & 1) && (icol != jcol[nt])) mval = -100.0f;
                const float* bp = bias_table + (fi0 + gjv[nt]) * 16 + h;
                #pragma unroll
                for (int r = 0; r < 4; ++r)
                    s4[mt][nt][r] = s4[mt][nt][r] * scale + bp[r * 16] + mval;
            }
        }

        #pragma unroll
        for (int mt = 0; mt < 4; ++mt)
            #pragma unroll
            for (int r = 0; r < 4; ++r) {
                float m = fmaxf(fmaxf(s4[mt][0][r], s4[mt][1][r]),
                                fmaxf(s4[mt][2][r], s4[mt][3][r]));
                m = fmaxf(m, __shfl_xor(m, 1));
                m = fmaxf(m, __shfl_xor(m, 2));
                m = fmaxf(m, __shfl_xor(m, 4));
                m = fmaxf(m, __shfl_xor(m, 8));
                float loc = 0.0f;
                #pragma unroll
                for (int nt = 0; nt < 4; ++nt) {
                    s4[mt][nt][r] = __expf(s4[mt][nt][r] - m);
                    loc += s4[mt][nt][r];
                }
                loc += __shfl_xor(loc, 1);
                loc += __shfl_xor(loc, 2);
                loc += __shfl_xor(loc, 4);
                loc += __shfl_xor(loc, 8);
                const float inv = 1.0f / loc;
                const int row = (mt << 4) + (quad << 2) + r;
                #pragma unroll
                for (int nt = 0; nt < 4; ++nt)
                    pbf[row * 72 + (nt << 4) + l15] = f2bf(s4[mt][nt][r] * inv);
            }

        short8 pa[4][2], va[2][2];
        #pragma unroll
        for (int mt = 0; mt < 4; ++mt)
            #pragma unroll
            for (int ks = 0; ks < 2; ++ks)
                pa[mt][ks] = *(const short8*)&pbf[((mt << 4) + l15) * 72 + (ks << 5) + (quad << 3)];
        #pragma unroll
        for (int nt = 0; nt < 2; ++nt)
            #pragma unroll
            for (int ks = 0; ks < 2; ++ks)
                va[nt][ks] = *(const short8*)&vT[((nt << 4) + l15) * 72 + (ks << 5) + (quad << 3)];

        #pragma unroll
        for (int mt = 0; mt < 4; ++mt)
            #pragma unroll
            for (int nt = 0; nt < 2; ++nt) {
                floatx4 acc = fz;
                acc = __builtin_amdgcn_mfma_f32_16x16x32_bf16(pa[mt][0], va[nt][0], acc, 0, 0, 0);
                acc = __builtin_amdgcn_mfma_f32_16x16x32_bf16(pa[mt][1], va[nt][1], acc, 0, 0, 0);
                const int pi = ((mt << 1) + nt) << 1;
                po[hh][pi]     = (unsigned int)f2bf(acc[0]) | ((unsigned int)f2bf(acc[1]) << 16);
                po[hh][pi + 1] = (unsigned int)f2bf(acc[2]) | ((unsigned int)f2bf(acc[3]) << 16);
            }
    }
    __syncthreads();

    #pragma unroll
    for (int hh = 0; hh < 4; ++hh) {
        const int ch0 = (((wave << 2) + hh) << 5) + l15;
        #pragma unroll
        for (int mt = 0; mt < 4; ++mt)
            #pragma unroll
            for (int nt = 0; nt < 2; ++nt) {
                const int pi = ((mt << 1) + nt) << 1;
                #pragma unroll
                for (int r = 0; r < 4; ++r) {
                    const int row = (mt << 4) + (quad << 2) + r;
                    const unsigned int w = po[hh][pi + (r >> 1)];
                    xs[row * 520 + ch0 + (nt << 4)] =
                        (unsigned short)((w >> ((r & 1) << 4)) & 0xffffu);
                }
            }
    }
    __syncthreads();

    const unsigned short* pwb = wbf + 786432;
    for (int pass = 0; pass < 2; ++pass) {
        const int co0 = (wave << 7) + (pass << 6);
        floatx4 acc[4][4];
        #pragma unroll
        for (int mt = 0; mt < 4; ++mt)
            #pragma unroll
            for (int nt = 0; nt < 4; ++nt) acc[mt][nt] = fz;

        const unsigned short* wp = pwb + (co0 + l15) * 512 + (quad << 3);

        #pragma unroll 2
        for (int kk = 0; kk < 512; kk += 32) {
            short8 a[4], bfr[4];
            #pragma unroll
            for (int mt = 0; mt < 4; ++mt)
                a[mt] = *(const short8*)&xs[((mt << 4) + l15) * 520 + kk + (quad << 3)];
            #pragma unroll
            for (int nt = 0; nt < 4; ++nt)
                bfr[nt] = *(const short8*)(wp + (nt << 4) * 512 + kk);
            #pragma unroll
            for (int nt = 0; nt < 4; ++nt)
                #pragma unroll
                for (int mt = 0; mt < 4; ++mt)
                    acc[mt][nt] = __builtin_amdgcn_mfma_f32_16x16x32_bf16(a[mt], bfr[nt], acc[mt][nt], 0, 0, 0);
        }

        #pragma unroll
        for (int nt = 0; nt < 4; ++nt) {
            const float pb_ = proj_b[co0 + (nt << 4) + l15];
            #pragma unroll
            for (int mt = 0; mt < 4; ++mt)
                #pragma unroll
                for (int r = 0; r < 4; ++r) {
                    const int tok = (mt << 4) + (quad << 2) + r;
                    const int ty = tok >> 3, tx = tok & 7;
                    const int gh = ((wy << 3) + ty + 4) & 63;
                    const int gw = ((wx << 3) + tx + 4) & 63;
                    out[(((b << 12) + (gh << 6) + gw) << 9) + co0 + (nt << 4) + l15] =
                        acc[mt][nt][r] + pb_;
                }
        }
    }
}

// ---------------------------------------------------------------------------
extern "C" void kernel_launch(void* const* d_in, const int* in_sizes, int n_in,
                              void* d_out, int out_size, void* d_ws, size_t ws_size,
                              hipStream_t stream) {
    const float* query      = (const float*)d_in[0];
    const float* qkv_w      = (const float*)d_in[1];
    const float* qkv_b      = (const float*)d_in[2];
    const float* proj_w     = (const float*)d_in[3];
    const float* proj_b     = (const float*)d_in[4];
    const float* bias_table = (const float*)d_in[5];
    // d_in[6] = rel_index (closed-form, unused), d_in[7]=H, d_in[8]=W

    unsigned short* wbf = (unsigned short*)d_ws;              // 2 MiB weights
    unsigned short* xw  = wbf + 1048576;                      // 64 MiB tiled windows
    unsigned short* yw  = xw + 33554432;                      // 64 MiB attention output

    const size_t needC2 = (size_t)(1048576 + 33554432 + 33554432) * sizeof(unsigned short);
    const size_t needB  = (size_t)(1048576 + 33554432) * sizeof(unsigned short);

    if (ws_size >= needC2) {
        hipLaunchKernelGGL(wcvt,     dim3(1024),  dim3(256), 0, stream, qkv_w, proj_w, wbf);
        hipLaunchKernelGGL(xcvt,     dim3(16384), dim3(256), 0, stream, query, xw);
        hipLaunchKernelGGL(k_fused2, dim3(1024),  dim3(256), 0, stream,
                           wbf, xw, yw, qkv_b, proj_b, bias_table, (float*)d_out);
    } else if (ws_size >= needB) {
        hipLaunchKernelGGL(wcvt,       dim3(1024),  dim3(256), 0, stream, qkv_w, proj_w, wbf);
        hipLaunchKernelGGL(xcvt,       dim3(16384), dim3(256), 0, stream, query, xw);
        hipLaunchKernelGGL(k_fused_r1, dim3(1024),  dim3(256), 0, stream,
                           wbf, xw, qkv_b, proj_b, bias_table, (float*)d_out);
    } else {
        hipLaunchKernelGGL(wcvt,     dim3(1024), dim3(256), 0, stream, qkv_w, proj_w, wbf);
        hipLaunchKernelGGL(k_legacy, dim3(1024), dim3(256), 0, stream,
                           query, wbf, qkv_b, proj_b, bias_table, (float*)d_out);
    }
}

// Round 7
// 508.430 us; speedup vs baseline: 1.2940x; 1.2940x over previous
//
#include <hip/hip_runtime.h>

// ShiftWindowMSA (Swin) fused kernels for MI355X (gfx950).
// B=16, H=W=64, C=512, NH=16, hd=32, WS=8, SS=4 -> 1024 windows x 64 tokens.
//
// R7: k_qa = R5 k_qkv's window-sharing GEMM schedule (4 blocks/window ->
// 1 MB/XCD window footprint, measured 69 MB FETCH) + R2/R6's in-LDS
// attention (q/k/vT never touch HBM; R5's fatal 210 MB qkvbuf write gone).
// 1 wave = 1 head, zero barriers, 16384 independent waves.
// Then k_proj2 (R5-proven) reads yw and scatters to out.
// Evidence: R6 (664us) showed fused-per-window kernels thrash L2 (340MB
// FETCH: 64win x 64KB + 2MB weights > 4MB L2/XCD); R5's k_qkv showed the
// 4-blocks-per-window mapping stays L2-resident but was write-bound.
// ws >= 130 MiB confirmed (R6 engaged this tier). Tier B fallback = R1 path.
// NEVER __launch_bounds__(256,3) with 96-reg acc (R2: spill catastrophe).

typedef short  short8  __attribute__((ext_vector_type(8)));
typedef short  short4v __attribute__((ext_vector_type(4)));
typedef float  floatx4 __attribute__((ext_vector_type(4)));

#define DEVI static __device__ __forceinline__

DEVI unsigned short f2bf(float f) {
    union { float f; unsigned int u; } v;
    v.f = f;
    return (unsigned short)((v.u + 0x7fffu + ((v.u >> 16) & 1u)) >> 16);
}

// ---------------------------------------------------------------------------
// wcvt: qkv_w (1536x512) then proj_w (512x512) fp32 -> bf16 into wbf.
// ---------------------------------------------------------------------------
__global__ void wcvt(const float* __restrict__ qkv_w,
                     const float* __restrict__ proj_w,
                     unsigned short* __restrict__ wbf) {
    const int idx = ((blockIdx.x << 8) + threadIdx.x) << 2;
    const float* src = (idx < 786432) ? (qkv_w + idx) : (proj_w + (idx - 786432));
    const floatx4 v = *(const floatx4*)src;
    short4v o;
    o[0] = (short)f2bf(v[0]); o[1] = (short)f2bf(v[1]);
    o[2] = (short)f2bf(v[2]); o[3] = (short)f2bf(v[3]);
    *(short4v*)(wbf + idx) = o;
}

// ---------------------------------------------------------------------------
// xcvt: gather cyclic-shifted windows of query -> xw bf16 [win][kc][tok][32].
// Grid 16384; window w handled by blocks with bid%8 == w/128 (XCD grouping).
// ---------------------------------------------------------------------------
__global__ void xcvt(const float* __restrict__ query,
                     unsigned short* __restrict__ xw) {
    const int bid = blockIdx.x;
    const int x   = bid & 7;
    const int s   = bid >> 3;                           // 0..2047
    const int win = (x << 7) + (s >> 4);
    const int rem = ((s & 15) << 8) + threadIdx.x;      // 0..4095
    const int jc  = rem & 3;                            // 8-short chunk in 32
    const int tok = (rem >> 2) & 63;
    const int kc  = rem >> 8;                           // 0..15
    const int b   = win >> 6, wy = (win >> 3) & 7, wx = win & 7;
    const int ty  = tok >> 3, tx = tok & 7;
    const int gh  = ((wy << 3) + ty + 4) & 63;
    const int gw  = ((wx << 3) + tx + 4) & 63;
    const float* src = query + (((b << 12) + (gh << 6) + gw) << 9) + (kc << 5) + (jc << 3);
    const floatx4 v0 = *(const floatx4*)src;
    const floatx4 v1 = *(const floatx4*)(src + 4);
    short8 sv;
    sv[0] = (short)f2bf(v0[0]); sv[1] = (short)f2bf(v0[1]);
    sv[2] = (short)f2bf(v0[2]); sv[3] = (short)f2bf(v0[3]);
    sv[4] = (short)f2bf(v1[0]); sv[5] = (short)f2bf(v1[1]);
    sv[6] = (short)f2bf(v1[2]); sv[7] = (short)f2bf(v1[3]);
    *(short8*)(xw + (win << 15) + (kc << 11) + (tok << 5) + (jc << 3)) = sv;
}

// ---------------------------------------------------------------------------
// k_qa: grid 4096 = (window, head-chunk). 4 waves/block, wave = head
// h = hc*4+wave. QKV GEMM (R5 k_qkv K-loop, window streamed once, L2-hot) ->
// q/k/vT staged to wave-private swizzled LDS (R2 layout) -> QK^T -> softmax
// -> PV (R6 code) -> y head-tile (2 KB) to yw. No barriers.
// ---------------------------------------------------------------------------
__global__ __launch_bounds__(256, 2)
void k_qa(const unsigned short* __restrict__ wbf,
          const unsigned short* __restrict__ xw,
          unsigned short* __restrict__ yw,
          const float* __restrict__ qkv_b,
          const float* __restrict__ bias_table)
{
    __shared__ __align__(16) unsigned short smem[24576];   // 4 waves * 6144

    const int tid  = threadIdx.x;
    const int lane = tid & 63;
    const int l15  = lane & 15;
    const int quad = lane >> 4;
    const int wave = tid >> 6;

    const int bid = blockIdx.x;
    const int x   = bid & 7;
    const int s   = bid >> 3;                           // 0..511
    const int win = (x << 7) + (s >> 2);
    const int hc  = s & 3;
    const int h   = (hc << 2) + wave;

    const int wy  = (win >> 3) & 7;
    const int wx  = win & 7;
    const int mid = ((wy == 7) ? 2 : 0) | ((wx == 7) ? 1 : 0);

    unsigned short* wbs = smem + wave * 6144;
    unsigned short* qbf = wbs;                          // [64][32] swizzled
    unsigned short* kbf = wbs + 2048;                   // [64][32] swizzled
    unsigned short* vT  = wbs + 4096;                   // [32][64] swizzled
    unsigned short* pbf = wbs;                          // [64][64] swizzled, overlays q+k

    const int sw4 = (l15 & 3) ^ (l15 >> 2);             // q/k read swizzle
    const int sw8 = (l15 & 7) ^ (l15 >> 3);             // vT/p read swizzle

    const unsigned short* xa = xw + (win << 15) + (l15 << 5) + (quad << 3);
    const float scale = 0.17677669529663687f;           // 1/sqrt(32)
    const floatx4 fz = {0.f, 0.f, 0.f, 0.f};

    // ---------------- QKV projection for this head (R5 k_qkv K-loop) --------
    floatx4 accq[4][2], acck[4][2], accv[4][2];
    #pragma unroll
    for (int mt = 0; mt < 4; ++mt)
        #pragma unroll
        for (int nt = 0; nt < 2; ++nt) { accq[mt][nt] = fz; acck[mt][nt] = fz; accv[mt][nt] = fz; }

    const unsigned short* wq = wbf + ((h << 5) + l15) * 512 + (quad << 3);
    const unsigned short* wk = wq + 262144;
    const unsigned short* wv = wk + 262144;

    #pragma unroll 2
    for (int kk = 0; kk < 512; kk += 32) {
        short8 a[4], bq[2], bk2[2], bv2[2];
        #pragma unroll
        for (int mt = 0; mt < 4; ++mt)
            a[mt] = *(const short8*)(xa + (kk << 6) + (mt << 9));
        #pragma unroll
        for (int nt = 0; nt < 2; ++nt) {
            const int ro = (nt << 4) * 512 + kk;
            bq[nt]  = *(const short8*)(wq + ro);
            bk2[nt] = *(const short8*)(wk + ro);
            bv2[nt] = *(const short8*)(wv + ro);
        }
        #pragma unroll
        for (int nt = 0; nt < 2; ++nt)
            #pragma unroll
            for (int mt = 0; mt < 4; ++mt) {
                accq[mt][nt] = __builtin_amdgcn_mfma_f32_16x16x32_bf16(a[mt], bq[nt],  accq[mt][nt], 0, 0, 0);
                acck[mt][nt] = __builtin_amdgcn_mfma_f32_16x16x32_bf16(a[mt], bk2[nt], acck[mt][nt], 0, 0, 0);
                accv[mt][nt] = __builtin_amdgcn_mfma_f32_16x16x32_bf16(a[mt], bv2[nt], accv[mt][nt], 0, 0, 0);
            }
    }

    // ---- bias + stage q,k (swizzled) and vT (swizzled) into LDS (R2 code) ---
    #pragma unroll
    for (int nt = 0; nt < 2; ++nt) {
        const int cix = (h << 5) + (nt << 4) + l15;
        const float bq_ = qkv_b[cix];
        const float bk_ = qkv_b[512 + cix];
        const float bv_ = qkv_b[1024 + cix];
        #pragma unroll
        for (int mt = 0; mt < 4; ++mt) {
            short4v vv;
            #pragma unroll
            for (int r = 0; r < 4; ++r) {
                const int row = (mt << 4) + (quad << 2) + r;
                const int ph  = (2 * nt + (l15 >> 3)) ^ (row & 3) ^ ((row >> 2) & 3);
                const int off = (row << 5) + (l15 & 7) + (ph << 3);
                qbf[off] = f2bf(accq[mt][nt][r] + bq_);
                kbf[off] = f2bf(acck[mt][nt][r] + bk_);
                vv[r] = (short)f2bf(accv[mt][nt][r] + bv_);
            }
            const int vph = (2 * mt + (quad >> 1)) ^ sw8;
            *(short4v*)&vT[(((nt << 4) + l15) << 6) + ((quad & 1) << 2) + (vph << 3)] = vv;
        }
    }
    // (no barrier: scratch is wave-private)

    // ---------------- Q K^T (R6 code) ----------------------------------------
    short8 qa[4], ka[4];
    #pragma unroll
    for (int t = 0; t < 4; ++t) {
        const int off = ((((t << 4) + l15)) << 5) + ((quad ^ sw4) << 3);
        qa[t] = *(const short8*)&qbf[off];
        ka[t] = *(const short8*)&kbf[off];
    }
    floatx4 s4[4][4];
    #pragma unroll
    for (int mt = 0; mt < 4; ++mt)
        #pragma unroll
        for (int nt = 0; nt < 4; ++nt)
            s4[mt][nt] = __builtin_amdgcn_mfma_f32_16x16x32_bf16(qa[mt], ka[nt], fz, 0, 0, 0);

    // ------- logits: scale + rel-pos bias (closed-form idx) + shift mask -----
    int  gjv[4]; bool jrow[4], jcol[4];
    #pragma unroll
    for (int nt = 0; nt < 4; ++nt) {
        const int j  = (nt << 4) + l15;
        const int j2 = 63 - j;
        gjv[nt]  = 15 * (j2 >> 3) + (j2 & 7);
        jrow[nt] = (j >> 3) < 4;
        jcol[nt] = (j & 7) < 4;
    }
    #pragma unroll
    for (int mt = 0; mt < 4; ++mt) {
        const int i0  = (mt << 4) + (quad << 2);
        const int fi0 = 15 * (i0 >> 3) + (i0 & 7);
        const bool irow = (i0 >> 3) < 4;
        const bool icol = (i0 & 7) == 0;
        #pragma unroll
        for (int nt = 0; nt < 4; ++nt) {
            float mval = 0.0f;
            if ((mid & 2) && (irow != jrow[nt])) mval = -100.0f;
            if ((mid & 1) && (icol != jcol[nt])) mval = -100.0f;
            const float* bp = bias_table + (fi0 + gjv[nt]) * 16 + h;
            #pragma unroll
            for (int r = 0; r < 4; ++r)
                s4[mt][nt][r] = s4[mt][nt][r] * scale + bp[r * 16] + mval;
        }
    }

    // ---- softmax (max-subtracted, normalized) -> P in swizzled LDS ----------
    #pragma unroll
    for (int mt = 0; mt < 4; ++mt)
        #pragma unroll
        for (int r = 0; r < 4; ++r) {
            float m = fmaxf(fmaxf(s4[mt][0][r], s4[mt][1][r]),
                            fmaxf(s4[mt][2][r], s4[mt][3][r]));
            m = fmaxf(m, __shfl_xor(m, 1));
            m = fmaxf(m, __shfl_xor(m, 2));
            m = fmaxf(m, __shfl_xor(m, 4));
            m = fmaxf(m, __shfl_xor(m, 8));
            float loc = 0.0f;
            #pragma unroll
            for (int nt = 0; nt < 4; ++nt) {
                s4[mt][nt][r] = __expf(s4[mt][nt][r] - m);
                loc += s4[mt][nt][r];
            }
            loc += __shfl_xor(loc, 1);
            loc += __shfl_xor(loc, 2);
            loc += __shfl_xor(loc, 4);
            loc += __shfl_xor(loc, 8);
            const float inv = 1.0f / loc;               // loc >= 1 (max entry = 1)
            const int row = (mt << 4) + (quad << 2) + r;
            #pragma unroll
            for (int nt = 0; nt < 4; ++nt) {
                const int ph = (2 * nt + (l15 >> 3)) ^ (row & 7) ^ ((row >> 3) & 1);
                pbf[(row << 6) + (l15 & 7) + (ph << 3)] = f2bf(s4[mt][nt][r] * inv);
            }
        }
    // (no barrier: pbf is wave-private)

    // ---------------- P V -> y head-tile to global yw ------------------------
    short8 pa[4][2], va[2][2];
    #pragma unroll
    for (int mt = 0; mt < 4; ++mt)
        #pragma unroll
        for (int ks = 0; ks < 2; ++ks)
            pa[mt][ks] = *(const short8*)&pbf[((((mt << 4) + l15)) << 6) + ((((ks << 2) + quad) ^ sw8) << 3)];
    #pragma unroll
    for (int nt = 0; nt < 2; ++nt)
        #pragma unroll
        for (int ks = 0; ks < 2; ++ks)
            va[nt][ks] = *(const short8*)&vT[((((nt << 4) + l15)) << 6) + ((((ks << 2) + quad) ^ sw8) << 3)];

    unsigned short* yh = yw + (win << 15) + (h << 11);
    #pragma unroll
    for (int mt = 0; mt < 4; ++mt)
        #pragma unroll
        for (int nt = 0; nt < 2; ++nt) {
            floatx4 acc = fz;
            acc = __builtin_amdgcn_mfma_f32_16x16x32_bf16(pa[mt][0], va[nt][0], acc, 0, 0, 0);
            acc = __builtin_amdgcn_mfma_f32_16x16x32_bf16(pa[mt][1], va[nt][1], acc, 0, 0, 0);
            #pragma unroll
            for (int r = 0; r < 4; ++r) {
                const int tok = (mt << 4) + (quad << 2) + r;
                yh[(tok << 5) + (nt << 4) + l15] = f2bf(acc[r]);
            }
        }
}

// ---------------------------------------------------------------------------
// k_proj2 (R5-proven): proj GEMM, token-split. Grid 1024 (1 block = 1 window);
// wave = 32 tok x 128 out-ch per pass (2 passes) -> acc[2][8].
// Window-reverse + reverse cyclic shift folded into the output scatter.
// ---------------------------------------------------------------------------
__global__ __launch_bounds__(256, 2)
void k_proj2(const unsigned short* __restrict__ wbf,
             const unsigned short* __restrict__ yw,
             const float* __restrict__ proj_b,
             float* __restrict__ out)
{
    const int tid  = threadIdx.x;
    const int lane = tid & 63;
    const int l15  = lane & 15;
    const int quad = lane >> 4;
    const int wave = tid >> 6;
    const int th   = wave & 1;                          // token half
    const int cq   = wave >> 1;                         // channel 128-half

    const int bid = blockIdx.x;
    const int x   = bid & 7;
    const int s   = bid >> 3;
    const int win = (x << 7) + s;
    const int b   = win >> 6;
    const int wy  = (win >> 3) & 7;
    const int wx  = win & 7;

    const unsigned short* ya  = yw + (win << 15) + (l15 << 5) + (quad << 3);
    const unsigned short* pwb = wbf + 786432;           // proj_w bf16
    const floatx4 fz = {0.f, 0.f, 0.f, 0.f};

    for (int pass = 0; pass < 2; ++pass) {
        const int co0 = (pass << 8) + (cq << 7);
        floatx4 acc[2][8];
        #pragma unroll
        for (int mt = 0; mt < 2; ++mt)
            #pragma unroll
            for (int nt = 0; nt < 8; ++nt) acc[mt][nt] = fz;

        const unsigned short* wp = pwb + (co0 + l15) * 512 + (quad << 3);

        #pragma unroll 2
        for (int kk = 0; kk < 512; kk += 32) {
            short8 a[2], bfr[8];
            #pragma unroll
            for (int mt = 0; mt < 2; ++mt)
                a[mt] = *(const short8*)(ya + (kk << 6) + (((th << 1) + mt) << 9));
            #pragma unroll
            for (int nt = 0; nt < 8; ++nt)
                bfr[nt] = *(const short8*)(wp + (nt << 4) * 512 + kk);
            #pragma unroll
            for (int nt = 0; nt < 8; ++nt)
                #pragma unroll
                for (int mt = 0; mt < 2; ++mt)
                    acc[mt][nt] = __builtin_amdgcn_mfma_f32_16x16x32_bf16(a[mt], bfr[nt], acc[mt][nt], 0, 0, 0);
        }

        #pragma unroll
        for (int nt = 0; nt < 8; ++nt) {
            const float pb_ = proj_b[co0 + (nt << 4) + l15];
            #pragma unroll
            for (int mt = 0; mt < 2; ++mt)
                #pragma unroll
                for (int r = 0; r < 4; ++r) {
                    const int tok = (((th << 1) + mt) << 4) + (quad << 2) + r;
                    const int ty = tok >> 3, tx = tok & 7;
                    const int gh = ((wy << 3) + ty + 4) & 63;
                    const int gw = ((wx << 3) + tx + 4) & 63;
                    out[(((b << 12) + (gh << 6) + gw) << 9) + co0 + (nt << 4) + l15] =
                        acc[mt][nt][r] + pb_;
                }
        }
    }
}

// ---------------------------------------------------------------------------
// Tier B fallback: R1's proven fused kernel (QKV+attn+proj from pre-tiled xw).
// ---------------------------------------------------------------------------
__global__ __launch_bounds__(256, 2)
void k_fused_r1(const unsigned short* __restrict__ wbf,
                const unsigned short* __restrict__ xw,
                const float* __restrict__ qkv_b,
                const float* __restrict__ proj_b,
                const float* __restrict__ bias_table,
                float* __restrict__ out)
{
    __shared__ __align__(16) unsigned short smem[33280];

    const int tid  = threadIdx.x;
    const int lane = tid & 63;
    const int l15  = lane & 15;
    const int quad = lane >> 4;
    const int wave = tid >> 6;

    const int win = blockIdx.x;
    const int b   = win >> 6;
    const int wy  = (win >> 3) & 7;
    const int wx  = win & 7;
    const int mid = ((wy == 7) ? 2 : 0) | ((wx == 7) ? 1 : 0);

    unsigned short* xs  = smem;
    unsigned short* wb  = smem + wave * 7424;
    unsigned short* qbf = wb;
    unsigned short* kbf = wb + 2560;
    unsigned short* vT  = wb + 5120;
    unsigned short* pbf = wb;

    const unsigned short* xa = xw + (win << 15) + (l15 << 5) + (quad << 3);
    const float scale = 0.17677669529663687f;
    const floatx4 fz = {0.f, 0.f, 0.f, 0.f};
    unsigned int po[4][16];

    for (int hh = 0; hh < 4; ++hh) {
        const int h = (wave << 2) + hh;
        floatx4 accq[4][2], acck[4][2], accv[4][2];
        #pragma unroll
        for (int mt = 0; mt < 4; ++mt)
            #pragma unroll
            for (int nt = 0; nt < 2; ++nt) { accq[mt][nt] = fz; acck[mt][nt] = fz; accv[mt][nt] = fz; }

        const unsigned short* wq = wbf + ((h << 5) + l15) * 512 + (quad << 3);
        const unsigned short* wk = wq + 512 * 512;
        const unsigned short* wv = wk + 512 * 512;

        #pragma unroll 2
        for (int kk = 0; kk < 512; kk += 32) {
            short8 a[4], bq[2], bk2[2], bv2[2];
            #pragma unroll
            for (int mt = 0; mt < 4; ++mt)
                a[mt] = *(const short8*)(xa + (kk << 6) + (mt << 9));
            #pragma unroll
            for (int nt = 0; nt < 2; ++nt) {
                const int ro = (nt << 4) * 512 + kk;
                bq[nt]  = *(const short8*)(wq + ro);
                bk2[nt] = *(const short8*)(wk + ro);
                bv2[nt] = *(const short8*)(wv + ro);
            }
            #pragma unroll
            for (int nt = 0; nt < 2; ++nt)
                #pragma unroll
                for (int mt = 0; mt < 4; ++mt) {
                    accq[mt][nt] = __builtin_amdgcn_mfma_f32_16x16x32_bf16(a[mt], bq[nt],  accq[mt][nt], 0, 0, 0);
                    acck[mt][nt] = __builtin_amdgcn_mfma_f32_16x16x32_bf16(a[mt], bk2[nt], acck[mt][nt], 0, 0, 0);
                    accv[mt][nt] = __builtin_amdgcn_mfma_f32_16x16x32_bf16(a[mt], bv2[nt], accv[mt][nt], 0, 0, 0);
                }
        }

        #pragma unroll
        for (int nt = 0; nt < 2; ++nt) {
            const int cix = (h << 5) + (nt << 4) + l15;
            const float bq_ = qkv_b[cix];
            const float bk_ = qkv_b[512 + cix];
            const float bv_ = qkv_b[1024 + cix];
            #pragma unroll
            for (int mt = 0; mt < 4; ++mt) {
                short4v vv;
                #pragma unroll
                for (int r = 0; r < 4; ++r) {
                    const int row = (mt << 4) + (quad << 2) + r;
                    qbf[row * 40 + (nt << 4) + l15] = f2bf(accq[mt][nt][r] + bq_);
                    kbf[row * 40 + (nt << 4) + l15] = f2bf(acck[mt][nt][r] + bk_);
                    vv[r] = (short)f2bf(accv[mt][nt][r] + bv_);
                }
                *(short4v*)&vT[((nt << 4) + l15) * 72 + (mt << 4) + (quad << 2)] = vv;
            }
        }

        short8 qa[4], ka[4];
        #pragma unroll
        for (int t = 0; t < 4; ++t) {
            qa[t] = *(const short8*)&qbf[((t << 4) + l15) * 40 + (quad << 3)];
            ka[t] = *(const short8*)&kbf[((t << 4) + l15) * 40 + (quad << 3)];
        }
        floatx4 s4[4][4];
        #pragma unroll
        for (int mt = 0; mt < 4; ++mt)
            #pragma unroll
            for (int nt = 0; nt < 4; ++nt)
                s4[mt][nt] = __builtin_amdgcn_mfma_f32_16x16x32_bf16(qa[mt], ka[nt], fz, 0, 0, 0);

        int  gjv[4]; bool jrow[4], jcol[4];
        #pragma unroll
        for (int nt = 0; nt < 4; ++nt) {
            const int j  = (nt << 4) + l15;
            const int j2 = 63 - j;
            gjv[nt]  = 15 * (j2 >> 3) + (j2 & 7);
            jrow[nt] = (j >> 3) < 4;
            jcol[nt] = (j & 7) < 4;
        }
        #pragma unroll
        for (int mt = 0; mt < 4; ++mt) {
            const int i0  = (mt << 4) + (quad << 2);
            const int fi0 = 15 * (i0 >> 3) + (i0 & 7);
            const bool irow = (i0 >> 3) < 4;
            const bool icol = (i0 & 7) == 0;
            #pragma unroll
            for (int nt = 0; nt < 4; ++nt) {
                float mval = 0.0f;
                if ((mid & 2) && (irow != jrow[nt])) mval = -100.0f;
                if ((mid & 1) && (icol != jcol[nt])) mval = -100.0f;
                const float* bp = bias_table + (fi0 + gjv[nt]) * 16 + h;
                #pragma unroll
                for (int r = 0; r < 4; ++r)
                    s4[mt][nt][r] = s4[mt][nt][r] * scale + bp[r * 16] + mval;
            }
        }

        #pragma unroll
        for (int mt = 0; mt < 4; ++mt)
            #pragma unroll
            for (int r = 0; r < 4; ++r) {
                float m = fmaxf(fmaxf(s4[mt][0][r], s4[mt][1][r]),
                                fmaxf(s4[mt][2][r], s4[mt][3][r]));
                m = fmaxf(m, __shfl_xor(m, 1));
                m = fmaxf(m, __shfl_xor(m, 2));
                m = fmaxf(m, __shfl_xor(m, 4));
                m = fmaxf(m, __shfl_xor(m, 8));
                float loc = 0.0f;
                #pragma unroll
                for (int nt = 0; nt < 4; ++nt) {
                    s4[mt][nt][r] = __expf(s4[mt][nt][r] - m);
                    loc += s4[mt][nt][r];
                }
                loc += __shfl_xor(loc, 1);
                loc += __shfl_xor(loc, 2);
                loc += __shfl_xor(loc, 4);
                loc += __shfl_xor(loc, 8);
                const float inv = 1.0f / loc;
                const int row = (mt << 4) + (quad << 2) + r;
                #pragma unroll
                for (int nt = 0; nt < 4; ++nt)
                    pbf[row * 72 + (nt << 4) + l15] = f2bf(s4[mt][nt][r] * inv);
            }

        short8 pa[4][2], va[2][2];
        #pragma unroll
        for (int mt = 0; mt < 4; ++mt)
            #pragma unroll
            for (int ks = 0; ks < 2; ++ks)
                pa[mt][ks] = *(const short8*)&pbf[((mt << 4) + l15) * 72 + (ks << 5) + (quad << 3)];
        #pragma unroll
        for (int nt = 0; nt < 2; ++nt)
            #pragma unroll
            for (int ks = 0; ks < 2; ++ks)
                va[nt][ks] = *(const short8*)&vT[((nt << 4) + l15) * 72 + (ks << 5) + (quad << 3)];

        #pragma unroll
        for (int mt = 0; mt < 4; ++mt)
            #pragma unroll
            for (int nt = 0; nt < 2; ++nt) {
                floatx4 acc = fz;
                acc = __builtin_amdgcn_mfma_f32_16x16x32_bf16(pa[mt][0], va[nt][0], acc, 0, 0, 0);
                acc = __builtin_amdgcn_mfma_f32_16x16x32_bf16(pa[mt][1], va[nt][1], acc, 0, 0, 0);
                const int pi = ((mt << 1) + nt) << 1;
                po[hh][pi]     = (unsigned int)f2bf(acc[0]) | ((unsigned int)f2bf(acc[1]) << 16);
                po[hh][pi + 1] = (unsigned int)f2bf(acc[2]) | ((unsigned int)f2bf(acc[3]) << 16);
            }
    }
    __syncthreads();

    #pragma unroll
    for (int hh = 0; hh < 4; ++hh) {
        const int ch0 = (((wave << 2) + hh) << 5) + l15;
        #pragma unroll
        for (int mt = 0; mt < 4; ++mt)
            #pragma unroll
            for (int nt = 0; nt < 2; ++nt) {
                const int pi = ((mt << 1) + nt) << 1;
                #pragma unroll
                for (int r = 0; r < 4; ++r) {
                    const int row = (mt << 4) + (quad << 2) + r;
                    const unsigned int w = po[hh][pi + (r >> 1)];
                    xs[row * 520 + ch0 + (nt << 4)] =
                        (unsigned short)((w >> ((r & 1) << 4)) & 0xffffu);
                }
            }
    }
    __syncthreads();

    const unsigned short* pwb = wbf + 786432;
    for (int pass = 0; pass < 2; ++pass) {
        const int co0 = (wave << 7) + (pass << 6);
        floatx4 acc[4][4];
        #pragma unroll
        for (int mt = 0; mt < 4; ++mt)
            #pragma unroll
            for (int nt = 0; nt < 4; ++nt) acc[mt][nt] = fz;

        const unsigned short* wp = pwb + (co0 + l15) * 512 + (quad << 3);

        #pragma unroll 2
        for (int kk = 0; kk < 512; kk += 32) {
            short8 a[4], bfr[4];
            #pragma unroll
            for (int mt = 0; mt < 4; ++mt)
                a[mt] = *(const short8*)&xs[((mt << 4) + l15) * 520 + kk + (quad << 3)];
            #pragma unroll
            for (int nt = 0; nt < 4; ++nt)
                bfr[nt] = *(const short8*)(wp + (nt << 4) * 512 + kk);
            #pragma unroll
            for (int nt = 0; nt < 4; ++nt)
                #pragma unroll
                for (int mt = 0; mt < 4; ++mt)
                    acc[mt][nt] = __builtin_amdgcn_mfma_f32_16x16x32_bf16(a[mt], bfr[nt], acc[mt][nt], 0, 0, 0);
        }

        #pragma unroll
        for (int nt = 0; nt < 4; ++nt) {
            const float pb_ = proj_b[co0 + (nt << 4) + l15];
            #pragma unroll
            for (int mt = 0; mt < 4; ++mt)
                #pragma unroll
                for (int r = 0; r < 4; ++r) {
                    const int tok = (mt << 4) + (quad << 2) + r;
                    const int ty = tok >> 3, tx = tok & 7;
                    const int gh = ((wy << 3) + ty + 4) & 63;
                    const int gw = ((wx << 3) + tx + 4) & 63;
                    out[(((b << 12) + (gh << 6) + gw) << 9) + co0 + (nt << 4) + l15] =
                        acc[mt][nt][r] + pb_;
                }
        }
    }
}

// ---------------------------------------------------------------------------
extern "C" void kernel_launch(void* const* d_in, const int* in_sizes, int n_in,
                              void* d_out, int out_size, void* d_ws, size_t ws_size,
                              hipStream_t stream) {
    const float* query      = (const float*)d_in[0];
    const float* qkv_w      = (const float*)d_in[1];
    const float* qkv_b      = (const float*)d_in[2];
    const float* proj_w     = (const float*)d_in[3];
    const float* proj_b     = (const float*)d_in[4];
    const float* bias_table = (const float*)d_in[5];
    // d_in[6] = rel_index (closed-form, unused), d_in[7]=H, d_in[8]=W

    unsigned short* wbf = (unsigned short*)d_ws;              // 2 MiB weights
    unsigned short* xw  = wbf + 1048576;                      // 64 MiB tiled windows
    unsigned short* yw  = xw + 33554432;                      // 64 MiB attention output

    const size_t needA = (size_t)(1048576 + 33554432 + 33554432) * sizeof(unsigned short);
    const size_t needB = (size_t)(1048576 + 33554432) * sizeof(unsigned short);

    if (ws_size >= needA) {
        hipLaunchKernelGGL(wcvt,    dim3(1024),  dim3(256), 0, stream, qkv_w, proj_w, wbf);
        hipLaunchKernelGGL(xcvt,    dim3(16384), dim3(256), 0, stream, query, xw);
        hipLaunchKernelGGL(k_qa,    dim3(4096),  dim3(256), 0, stream,
                           wbf, xw, yw, qkv_b, bias_table);
        hipLaunchKernelGGL(k_proj2, dim3(1024),  dim3(256), 0, stream,
                           wbf, yw, proj_b, (float*)d_out);
    } else if (ws_size >= needB) {
        hipLaunchKernelGGL(wcvt,       dim3(1024),  dim3(256), 0, stream, qkv_w, proj_w, wbf);
        hipLaunchKernelGGL(xcvt,       dim3(16384), dim3(256), 0, stream, query, xw);
        hipLaunchKernelGGL(k_fused_r1, dim3(1024),  dim3(256), 0, stream,
                           wbf, xw, qkv_b, proj_b, bias_table, (float*)d_out);
    }
}